// Round 1
// baseline (211.806 us; speedup 1.0000x reference)
//
#include <hip/hip_runtime.h>

// SABR IV surface, specialized for BETA=1, R=Q=0, RHO=-0.7, VOLVOL=0.3.
// With BETA=1: x=1, A=v, F=p, logFK=-log(m) -> output independent of price.
// out[i,j,t,m] = v*B(t)                      if m==1.0
//              = v*B(t)*Phi(m)/(Chi(m)+1e-8) otherwise
// B(t) = 1 + t*(c1*v + c2), Phi = 0.3*(-log m)/v,
// Chi = log((sqrt(1 + 1.4*Phi + Phi^2) + Phi + 0.7)/1.7)
//
// R5: wave-private LDS transpose, NO __syncthreads. Each wave transposes its
// 64 pairs through its own 6.4 KB LDS slice (only lgkmcnt ordering needed),
// so each wave flows compute->store independently -- removes the block-wide
// barrier convoy that left store-issue bubbles (kernel ~50us vs 33us write
// floor in R4). Plain float4 stores (nt regressed +7us in R3).
//
// R6 (this round): resubmit unchanged -- previous bench was an MI355X
// container infra failure; need baseline counters before editing.

#define THREADS 256
#define VALS_PER_PAIR 25
#define WAVE 64

__device__ __forceinline__ float fast_ln(float x) {
    // v_log_f32 gives log2(x); scale by ln(2)
    return __builtin_amdgcn_logf(x) * 0.6931471805599453f;
}

__global__ __launch_bounds__(THREADS)
void sabr_kernel(const float* __restrict__ vol, float* __restrict__ out) {
    __shared__ float sm[THREADS * VALS_PER_PAIR];  // 25.6 KB -> 6 blocks/CU

    const int tid   = threadIdx.x;
    const int wave  = tid >> 6;
    const int lane  = tid & 63;
    const int pair0 = blockIdx.x * THREADS;
    const float v   = vol[pair0 + tid];

    // wave-private LDS slice: 64 pairs * 25 vals = 1600 floats
    float* smw = sm + wave * (WAVE * VALS_PER_PAIR);

    // Constants
    const float c1 = -0.0525f;                       // RHO*VOLVOL/4
    const float c2 = 0.09f * 0.53f / 24.0f;          // VOLVOL^2*(2-3*RHO^2)/24
    // cPhi[m] = VOLVOL * (-log(m)); m = {0.7, 0.85, 1.0, 1.15, 1.3}
    const float cPhi[5] = { 0.3f * 0.35667494393873245f,
                            0.3f * 0.1625189294977749f,
                            0.0f,
                            0.3f * -0.13976194237515863f,
                            0.3f * -0.26236426446749106f };

    float g[5];
    const float inv_v = __builtin_amdgcn_rcpf(v);
#pragma unroll
    for (int mi = 0; mi < 5; ++mi) {
        if (mi == 2) { g[2] = 1.0f; continue; }
        const float Phi = cPhi[mi] * inv_v;
        const float arg = (__builtin_amdgcn_sqrtf(1.0f + 1.4f * Phi + Phi * Phi)
                           + Phi + 0.7f) * (1.0f / 1.7f);
        const float Chi = fast_ln(arg);
        g[mi] = Phi * __builtin_amdgcn_rcpf(Chi + 1e-8f);
    }

    const float slope = c1 * v + c2;
#pragma unroll
    for (int ti = 0; ti < 5; ++ti) {
        const float vB = v * (1.0f + (float)ti * slope);
#pragma unroll
        for (int mi = 0; mi < 5; ++mi) {
            smw[lane * VALS_PER_PAIR + ti * 5 + mi] = vB * g[mi];
        }
    }
    // No __syncthreads: each wave reads only its own LDS slice; the compiler's
    // lgkmcnt wait orders the wave's own writes before its reads.

    // Wave's output range is contiguous: 64*25 = 1600 floats = 400 float4
    float4* __restrict__ out4 =
        (float4*)(out + (size_t)(pair0 + wave * WAVE) * VALS_PER_PAIR);
    const float4* __restrict__ sm4 = (const float4*)smw;
#pragma unroll
    for (int k = lane; k < (WAVE * VALS_PER_PAIR) / 4; k += WAVE) {
        out4[k] = sm4[k];
    }
}

extern "C" void kernel_launch(void* const* d_in, const int* in_sizes, int n_in,
                              void* d_out, int out_size, void* d_ws, size_t ws_size,
                              hipStream_t stream) {
    const float* vol = (const float*)d_in[0];
    // d_in[1] (price) is unused: with BETA=1 and R=Q=0 the output is price-independent.
    float* out = (float*)d_out;
    const int npair = in_sizes[0];          // 4096*512 = 2097152
    const int grid  = npair / THREADS;      // 8192 blocks
    sabr_kernel<<<grid, THREADS, 0, stream>>>(vol, out);
}

// Round 2
// 209.125 us; speedup vs baseline: 1.0128x; 1.0128x over previous
//
#include <hip/hip_runtime.h>

// SABR IV surface, specialized for BETA=1, R=Q=0, RHO=-0.7, VOLVOL=0.3.
// With BETA=1: x=1, A=v, F=p, logFK=-log(m) -> output independent of price.
// out[i,j,t,m] = v*B(t)                      if m==1.0
//              = v*B(t)*Phi(m)/(Chi(m)+1e-8) otherwise
// B(t) = 1 + t*(c1*v + c2), Phi = 0.3*(-log m)/v,
// Chi = log((sqrt(1 + 1.4*Phi + Phi^2) + Phi + 0.7)/1.7)
//
// R7: store-duty-cycle fix. R6 analysis: kernel ~78us vs 35us traffic floor,
// while the harness fill kernel proves 6.3 TB/s writes. Each wave spent
// ~1300cyc in load+compute+LDS prelude to issue only ~6.25KB of stores (~8%
// store duty) -> ~5 B/cyc/CU, matching observed ~4.4. Fix: BATCH=4 sub-tiles
// of 256 pairs per block (grid 8192->2048). All 4 vol loads issue up-front;
// full unroll lets sub-batch s+1 compute/LDS overlap sub-batch s's
// outstanding stores (distinct regs, no vmcnt drain between batches).
// LDS unchanged 25.6KB, wave-private slice reused in-order (DS pipe is
// in-order per wave; no barrier needed).

#define THREADS 256
#define BATCH 4
#define VALS_PER_PAIR 25
#define WAVE 64

__device__ __forceinline__ float fast_ln(float x) {
    // v_log_f32 gives log2(x); scale by ln(2)
    return __builtin_amdgcn_logf(x) * 0.6931471805599453f;
}

__global__ __launch_bounds__(THREADS, 4)
void sabr_kernel(const float* __restrict__ vol, float* __restrict__ out) {
    __shared__ float sm[THREADS * VALS_PER_PAIR];  // 25.6 KB

    const int tid   = threadIdx.x;
    const int wave  = tid >> 6;
    const int lane  = tid & 63;
    const int base  = blockIdx.x * (THREADS * BATCH);

    // Issue all BATCH loads up-front: one HBM latency exposure, coalesced.
    float v[BATCH];
#pragma unroll
    for (int s = 0; s < BATCH; ++s)
        v[s] = vol[base + s * THREADS + tid];

    // wave-private LDS slice: 64 pairs * 25 vals = 1600 floats
    float* smw = sm + wave * (WAVE * VALS_PER_PAIR);

    // Constants
    const float c1 = -0.0525f;                       // RHO*VOLVOL/4
    const float c2 = 0.09f * 0.53f / 24.0f;          // VOLVOL^2*(2-3*RHO^2)/24
    // cPhi[m] = VOLVOL * (-log(m)); m = {0.7, 0.85, 1.0, 1.15, 1.3}
    const float cPhi[5] = { 0.3f * 0.35667494393873245f,
                            0.3f * 0.1625189294977749f,
                            0.0f,
                            0.3f * -0.13976194237515863f,
                            0.3f * -0.26236426446749106f };

#pragma unroll
    for (int s = 0; s < BATCH; ++s) {
        const float vs = v[s];

        float g[5];
        const float inv_v = __builtin_amdgcn_rcpf(vs);
#pragma unroll
        for (int mi = 0; mi < 5; ++mi) {
            if (mi == 2) { g[2] = 1.0f; continue; }
            const float Phi = cPhi[mi] * inv_v;
            const float arg = (__builtin_amdgcn_sqrtf(1.0f + 1.4f * Phi + Phi * Phi)
                               + Phi + 0.7f) * (1.0f / 1.7f);
            const float Chi = fast_ln(arg);
            g[mi] = Phi * __builtin_amdgcn_rcpf(Chi + 1e-8f);
        }

        const float slope = c1 * vs + c2;
#pragma unroll
        for (int ti = 0; ti < 5; ++ti) {
            const float vB = vs * (1.0f + (float)ti * slope);
#pragma unroll
            for (int mi = 0; mi < 5; ++mi) {
                smw[lane * VALS_PER_PAIR + ti * 5 + mi] = vB * g[mi];
            }
        }
        // No barrier: wave reads only its own slice; same-wave DS ops are
        // processed in order, so batch s reads complete before batch s+1
        // writes land, and the compiler's lgkmcnt orders writes->reads.

        // Wave's output range for this sub-batch: 64*25 = 1600 floats
        float4* __restrict__ out4 =
            (float4*)(out + (size_t)(base + s * THREADS + wave * WAVE) * VALS_PER_PAIR);
        const float4* __restrict__ sm4 = (const float4*)smw;
#pragma unroll
        for (int kk = 0; kk < 6; ++kk)
            out4[kk * WAVE + lane] = sm4[kk * WAVE + lane];
        if (lane < 16)
            out4[6 * WAVE + lane] = sm4[6 * WAVE + lane];
    }
}

extern "C" void kernel_launch(void* const* d_in, const int* in_sizes, int n_in,
                              void* d_out, int out_size, void* d_ws, size_t ws_size,
                              hipStream_t stream) {
    const float* vol = (const float*)d_in[0];
    // d_in[1] (price) is unused: with BETA=1 and R=Q=0 the output is price-independent.
    float* out = (float*)d_out;
    const int npair = in_sizes[0];              // 4096*512 = 2097152
    const int grid  = npair / (THREADS * BATCH); // 2048 blocks
    sabr_kernel<<<grid, THREADS, 0, stream>>>(vol, out);
}